// Round 2
// baseline (2889.657 us; speedup 1.0000x reference)
//
#include <hip/hip_runtime.h>
#include <cstdint>
#include <cstddef>

#define B_ 128
#define T_ 500
#define I_ 512
#define H_ 1024
#define O_ 11
#define BETA 0.9f
#define THRESH 1.0f

typedef __attribute__((ext_vector_type(4))) float f32x4;
typedef __attribute__((ext_vector_type(8))) short bf16x8;
typedef __attribute__((ext_vector_type(4))) unsigned int u32x4;

__device__ __forceinline__ unsigned short bf16_rne(float f) {
  unsigned int u = __float_as_uint(f);
  unsigned int r = u + 0x7FFFu + ((u >> 16) & 1u);
  return (unsigned short)(r >> 16);
}
__device__ __forceinline__ float bf16_to_f(unsigned short h) {
  return __uint_as_float(((unsigned int)h) << 16);
}

// ---------------- per-(64k-chunk, col) nnz counts --------------------------------------------
__global__ void k_csc_count(const float* __restrict__ mask, unsigned int* __restrict__ cntkc) {
  int id = blockIdx.x * 256 + threadIdx.x;  // 16384 threads
  int h = id & (H_ - 1);
  int kc = id >> 10;                         // 0..15
  unsigned c = 0;
  for (int k = kc * 64; k < kc * 64 + 64; ++k) c += (mask[(size_t)k * H_ + h] != 0.f);
  cntkc[kc * H_ + h] = c;
}

// ---------------- deterministic rank by nnz count (stable, O(n^2), one-time) ------------------
__global__ void k_rank(const unsigned int* __restrict__ cntkc, unsigned int* __restrict__ colcnt,
                       unsigned int* __restrict__ rank_g, unsigned int* __restrict__ src_g) {
  __shared__ unsigned int sc[H_];
  int h = threadIdx.x;
  unsigned c = 0;
  for (int p = 0; p < 16; ++p) c += cntkc[p * H_ + h];
  colcnt[h] = c;
  sc[h] = c;
  __syncthreads();
  unsigned r = 0;
  for (int j = 0; j < H_; ++j) {
    unsigned cj = sc[j];
    r += (cj < c) || (cj == c && j < h);
  }
  rank_g[h] = r;
  src_g[r] = (unsigned)h;
}

// ---------------- CSC fill at rank position; entry = w20 | shiftl5<<7 | wordbyte7 -------------
__global__ void k_csc_fill(const float* __restrict__ W_rec, const float* __restrict__ mask,
                           const unsigned int* __restrict__ cntkc,
                           const unsigned int* __restrict__ rank_g,
                           unsigned int* __restrict__ csc) {
  int id = blockIdx.x * 256 + threadIdx.x;
  int h = id & (H_ - 1);
  int kc = id >> 10;
  unsigned off = 0;
  for (int p = 0; p < kc; ++p) off += cntkc[p * H_ + h];
  unsigned dst = rank_g[h];
  for (int k = kc * 64; k < kc * 64 + 64; ++k) {
    float m = mask[(size_t)k * H_ + h];
    if (m != 0.f) {
      float w = W_rec[(size_t)k * H_ + h] * m;
      unsigned wb = (__float_as_uint(w) + 0x800u) & 0xFFFFF000u;  // 20-bit weight, rounded
      unsigned rk = rank_g[k];
      unsigned e = wb | ((31u - (rk & 31u)) << 7) | ((rk >> 5) << 2);
      if (off < 128u) csc[(size_t)off * H_ + dst] = e;
      ++off;
    }
  }
}

// zero-pad each rank-column to its 64-rank wave group's max; record group max
__global__ void k_csc_pad(unsigned int* __restrict__ csc, const unsigned int* __restrict__ colcnt,
                          const unsigned int* __restrict__ src_g, unsigned int* __restrict__ gmax) {
  __shared__ unsigned int sm[H_];
  int r = threadIdx.x;
  unsigned c = colcnt[src_g[r]];
  sm[r] = c;
  __syncthreads();
  int g = r >> 6;
  unsigned m = 0;
  for (int j = 0; j < 64; ++j) m = m > sm[g * 64 + j] ? m : sm[g * 64 + j];
  if ((r & 63) == 0) gmax[g] = m;
  for (unsigned j = c; j < m; ++j) csc[(size_t)j * H_ + r] = 0u;  // e=0 -> adds +0.0
}

// ---------------- Wt2 [1024][2048] bf16 built PERMUTED: row n=rank holds W_in[:, src[n]] ------
__global__ void k_build_wt(const float* __restrict__ W_in, const unsigned int* __restrict__ src_g,
                           unsigned short* __restrict__ Wt) {
  int n = blockIdx.y;
  int k2 = blockIdx.x * 256 + threadIdx.x;  // 0..2047
  int i = k2 >> 2;
  float w = W_in[i * H_ + (int)src_g[n]];
  unsigned short hi = bf16_rne(w);
  unsigned short v = (k2 & 2) ? bf16_rne(w - bf16_to_f(hi)) : hi;
  Wt[(size_t)n * 2048 + k2] = v;
}

// ---------------- xs2 chunk [128*Tc][2048] bf16: 4 bf16 per f32: {hi,lo,hi,lo} ----------------
__global__ void k_build_xs(const float* __restrict__ x, unsigned short* __restrict__ xs,
                           int t0, int Tc) {
  int id = blockIdx.x * 256 + threadIdx.x;
  int rr = id >> 7;
  int q = id & 127;
  int b = rr / Tc, tt = rr % Tc;
  const float4 v = *(const float4*)&x[((size_t)(b * T_ + t0 + tt)) * I_ + q * 4];
  alignas(16) unsigned short o[16];
  float vv[4] = {v.x, v.y, v.z, v.w};
#pragma unroll
  for (int j = 0; j < 4; ++j) {
    unsigned short hi = bf16_rne(vv[j]);
    unsigned short lo = bf16_rne(vv[j] - bf16_to_f(hi));
    o[4 * j + 0] = hi; o[4 * j + 1] = lo; o[4 * j + 2] = hi; o[4 * j + 3] = lo;
  }
  *(u32x4*)&xs[(size_t)rr * 2048 + q * 16] = *(u32x4*)o;
  *(u32x4*)&xs[(size_t)rr * 2048 + q * 16 + 8] = *(u32x4*)(o + 8);
}

// ---------------- split-bf16 GEMM (unchanged): drive[rr][rank] ---------------------------------
#define LDA 72
__global__ __launch_bounds__(512, 1) void k_gemm(const unsigned short* __restrict__ xs,
                                                 const unsigned short* __restrict__ Wt,
                                                 float* __restrict__ drive) {
  __shared__ __align__(16) unsigned short As[128 * LDA];
  __shared__ __align__(16) unsigned short Bs[256 * LDA];
  int mt = blockIdx.x, nt = blockIdx.y;
  int tid = threadIdx.x;
  int lane = tid & 63, w = tid >> 6;
  int wr = w >> 2, wc = w & 3;
  f32x4 acc[4][4] = {};
  int arow = tid >> 2, aq = tid & 3;
  int brow = tid >> 1, bh = tid & 1;
  const unsigned short* xsrow = xs + (size_t)(mt * 128 + arow) * 2048 + aq * 16;
  const unsigned short* wtrow = Wt + (size_t)(nt * 256 + brow) * 2048 + bh * 32;
  for (int kt = 0; kt < 32; ++kt) {
    u32x4 a0 = *(const u32x4*)(xsrow + kt * 64);
    u32x4 a1 = *(const u32x4*)(xsrow + kt * 64 + 8);
    u32x4 b0 = *(const u32x4*)(wtrow + kt * 64);
    u32x4 b1 = *(const u32x4*)(wtrow + kt * 64 + 8);
    u32x4 b2 = *(const u32x4*)(wtrow + kt * 64 + 16);
    u32x4 b3 = *(const u32x4*)(wtrow + kt * 64 + 24);
    __syncthreads();
    *(u32x4*)&As[arow * LDA + aq * 16] = a0;
    *(u32x4*)&As[arow * LDA + aq * 16 + 8] = a1;
    *(u32x4*)&Bs[brow * LDA + bh * 32] = b0;
    *(u32x4*)&Bs[brow * LDA + bh * 32 + 8] = b1;
    *(u32x4*)&Bs[brow * LDA + bh * 32 + 16] = b2;
    *(u32x4*)&Bs[brow * LDA + bh * 32 + 24] = b3;
    __syncthreads();
#pragma unroll
    for (int kk = 0; kk < 2; ++kk) {
      bf16x8 af[4], bf[4];
#pragma unroll
      for (int mi = 0; mi < 4; ++mi)
        af[mi] = *(const bf16x8*)&As[(wr * 64 + mi * 16 + (lane & 15)) * LDA + kk * 32 + (lane >> 4) * 8];
#pragma unroll
      for (int ni = 0; ni < 4; ++ni)
        bf[ni] = *(const bf16x8*)&Bs[(wc * 64 + ni * 16 + (lane & 15)) * LDA + kk * 32 + (lane >> 4) * 8];
#pragma unroll
      for (int mi = 0; mi < 4; ++mi)
#pragma unroll
        for (int ni = 0; ni < 4; ++ni)
          acc[mi][ni] = __builtin_amdgcn_mfma_f32_16x16x32_bf16(af[mi], bf[ni], acc[mi][ni], 0, 0, 0);
    }
  }
  int r0 = (lane >> 4) * 4, c0 = lane & 15;
#pragma unroll
  for (int mi = 0; mi < 4; ++mi) {
    int rowb = mt * 128 + wr * 64 + mi * 16 + r0;
#pragma unroll
    for (int ni = 0; ni < 4; ++ni) {
      int col = nt * 256 + wc * 64 + ni * 16 + c0;
#pragma unroll
      for (int r = 0; r < 4; ++r)
        drive[(size_t)(rowb + r) * H_ + col] = acc[mi][ni][r];
    }
  }
}

// ---------------- recurrent scan: bitmask spikes, ballot pack, conflict-free gather -----------
__device__ __forceinline__ void rsnn_step(const unsigned int* __restrict__ cscp, int jmax,
                                          const unsigned int* cur, unsigned int* nxt,
                                          float d, float bias, float& v, float& s, float& cnt,
                                          int lane, int wv) {
  float rec = 0.f;
#pragma unroll 4
  for (int j = 0; j < jmax; ++j) {
    unsigned e = cscp[(size_t)j * H_];
    unsigned bits = *(const unsigned int*)((const char*)cur + (e & 127u));  // 32 banks, bcast
    unsigned m = (unsigned)((int)(bits << ((e >> 7) & 31u)) >> 31);         // spike? all-ones
    rec += __uint_as_float(e & m & 0xFFFFF000u);
  }
  v = BETA * v + (d + bias) + rec;
  bool fire = v > THRESH;
  v -= fire ? THRESH : 0.f;
  s = fire ? 1.f : 0.f;
  cnt += s;
  unsigned long long bb = __ballot(fire);
  if (lane < 2) nxt[wv * 2 + lane] = (unsigned)(lane ? (bb >> 32) : bb);
  __syncthreads();
}

__global__ __launch_bounds__(1024, 1) void k_rsnn(
    const float* __restrict__ drive, const unsigned int* __restrict__ csc,
    const unsigned int* __restrict__ gmax_arr, const unsigned int* __restrict__ src_g,
    const float* __restrict__ h_bias, const float* __restrict__ W_out,
    const float* __restrict__ b_out,
    float* __restrict__ state_v, float* __restrict__ state_s, float* __restrict__ state_c,
    float* __restrict__ out, int t0, int Tc, int last) {
  __shared__ unsigned int bm0[32], bm1[32];
  __shared__ float red[H_];
  __shared__ float part[352];
  int tid = threadIdx.x;
  int b = blockIdx.x;
  int lane = tid & 63, wv = tid >> 6;
  int src = (int)src_g[tid];
  float bias = h_bias[src];
  int jmax = (int)gmax_arr[wv];
  float v, s, cnt;
  if (t0 == 0) { v = 0.f; s = 0.f; cnt = 0.f; }
  else { v = state_v[b * H_ + tid]; s = state_s[b * H_ + tid]; cnt = state_c[b * H_ + tid]; }
  {
    unsigned long long bb = __ballot(s > 0.f);
    if (lane < 2) bm0[wv * 2 + lane] = (unsigned)(lane ? (bb >> 32) : bb);
  }
  __syncthreads();
  const float* dptr = drive + (size_t)b * Tc * H_ + tid;
  const unsigned int* cscp = csc + tid;
  int t = 0;
  for (; t + 1 < Tc; t += 2) {
    rsnn_step(cscp, jmax, bm0, bm1, dptr[(size_t)t * H_], bias, v, s, cnt, lane, wv);
    rsnn_step(cscp, jmax, bm1, bm0, dptr[(size_t)(t + 1) * H_], bias, v, s, cnt, lane, wv);
  }
  if (t < Tc)
    rsnn_step(cscp, jmax, bm0, bm1, dptr[(size_t)t * H_], bias, v, s, cnt, lane, wv);

  if (!last) {
    state_v[b * H_ + tid] = v; state_s[b * H_ + tid] = s; state_c[b * H_ + tid] = cnt;
  } else {
    red[src] = cnt;  // scatter back to original h order (one-time)
    __syncthreads();
    if (tid < 352) {
      int o = tid >> 5, seg = tid & 31;
      float p = 0.f;
      for (int j = 0; j < 32; ++j) {
        int hh = seg * 32 + j;
        p += red[hh] * W_out[hh * O_ + o];
      }
      part[tid] = p;
    }
    __syncthreads();
    if (tid < O_) {
      float sum = 0.f;
      for (int g = 0; g < 32; ++g) sum += part[(tid << 5) + g];
      out[b * O_ + tid] = b_out[tid] + sum * (1.0f / (float)T_);
    }
  }
}

extern "C" void kernel_launch(void* const* d_in, const int* in_sizes, int n_in,
                              void* d_out, int out_size, void* d_ws, size_t ws_size,
                              hipStream_t stream) {
  (void)in_sizes; (void)n_in; (void)out_size;
  const float* x = (const float*)d_in[0];
  const float* W_in = (const float*)d_in[1];
  const float* W_rec = (const float*)d_in[2];
  const float* W_out = (const float*)d_in[3];
  const float* h_bias = (const float*)d_in[4];
  const float* b_out = (const float*)d_in[5];
  const float* mask = (const float*)d_in[6];
  float* out = (float*)d_out;

  char* ws = (char*)d_ws;
  size_t off = 0;
  auto alloc = [&](size_t bytes) {
    void* p = ws + off;
    off = (off + bytes + 255) & ~(size_t)255;
    return p;
  };
  unsigned short* Wt = (unsigned short*)alloc((size_t)H_ * 2048 * 2);
  unsigned int* csc = (unsigned int*)alloc((size_t)128 * H_ * 4);
  unsigned int* colcnt = (unsigned int*)alloc((size_t)H_ * 4);
  unsigned int* cntkc = (unsigned int*)alloc((size_t)16 * H_ * 4);
  unsigned int* gmaxb = (unsigned int*)alloc((size_t)16 * 4);
  unsigned int* rank_g = (unsigned int*)alloc((size_t)H_ * 4);
  unsigned int* src_g = (unsigned int*)alloc((size_t)H_ * 4);
  float* st_v = (float*)alloc((size_t)B_ * H_ * 4);
  float* st_s = (float*)alloc((size_t)B_ * H_ * 4);
  float* st_c = (float*)alloc((size_t)B_ * H_ * 4);
  size_t fixed = off;

  size_t per_t = (size_t)128 * 2048 * 2 + (size_t)128 * 1024 * 4;
  int Tc = 1;
  if (ws_size > fixed + per_t) Tc = (int)((ws_size - fixed) / per_t);
  if (Tc > T_) Tc = T_;
  if (Tc < 1) Tc = 1;
  unsigned short* xs = (unsigned short*)alloc((size_t)128 * Tc * 2048 * 2);
  float* drive = (float*)alloc((size_t)128 * Tc * 1024 * 4);

  k_csc_count<<<dim3(64), dim3(256), 0, stream>>>(mask, cntkc);
  k_rank<<<dim3(1), dim3(1024), 0, stream>>>(cntkc, colcnt, rank_g, src_g);
  k_csc_fill<<<dim3(64), dim3(256), 0, stream>>>(W_rec, mask, cntkc, rank_g, csc);
  k_csc_pad<<<dim3(1), dim3(1024), 0, stream>>>(csc, colcnt, src_g, gmaxb);
  k_build_wt<<<dim3(8, 1024), dim3(256), 0, stream>>>(W_in, src_g, Wt);

  for (int t0 = 0; t0 < T_; t0 += Tc) {
    int tc = (Tc < T_ - t0) ? Tc : (T_ - t0);
    k_build_xs<<<dim3(64 * tc), dim3(256), 0, stream>>>(x, xs, t0, tc);
    k_gemm<<<dim3(tc, 4), dim3(512), 0, stream>>>(xs, Wt, drive);
    k_rsnn<<<dim3(128), dim3(1024), 0, stream>>>(drive, csc, gmaxb, src_g, h_bias, W_out, b_out,
                                                 st_v, st_s, st_c, out, t0, tc,
                                                 (t0 + tc >= T_) ? 1 : 0);
  }
}

// Round 4
// 1466.451 us; speedup vs baseline: 1.9705x; 1.9705x over previous
//
#include <hip/hip_runtime.h>
#include <cstdint>
#include <cstddef>

#define B_ 128
#define T_ 500
#define I_ 512
#define H_ 1024
#define O_ 11
#define BETA 0.9f
#define THRESH 1.0f

typedef __attribute__((ext_vector_type(4))) float f32x4;
typedef __attribute__((ext_vector_type(8))) short bf16x8;
typedef __attribute__((ext_vector_type(4))) unsigned int u32x4;

__device__ __forceinline__ unsigned short bf16_rne(float f) {
  unsigned int u = __float_as_uint(f);
  unsigned int r = u + 0x7FFFu + ((u >> 16) & 1u);
  return (unsigned short)(r >> 16);
}
__device__ __forceinline__ float bf16_to_f(unsigned short h) {
  return __uint_as_float(((unsigned int)h) << 16);
}

// ---------------- CSR build: row r = outgoing edges of neuron r, 128 slots -------------------
// entry = (w22 << 10) | target10, w22 = round(W_eff * 2^23) clamped; pad: w=0, tgt=(slot&63)
__global__ void k_csr(const float* __restrict__ W_rec, const float* __restrict__ mask,
                      unsigned int* __restrict__ csr, unsigned int* __restrict__ rowhi) {
  int r = blockIdx.x * 4 + (threadIdx.x >> 6);  // one wave per row
  int lane = threadIdx.x & 63;
  const float* mrow = mask + (size_t)r * H_;
  const float* wrow = W_rec + (size_t)r * H_;
  unsigned cnt = 0;
  for (int c = 0; c < 16; ++c) {
    float m = mrow[c * 64 + lane];
    bool nz = (m != 0.f);
    unsigned long long bb = __ballot(nz);
    unsigned pos = cnt + (unsigned)__popcll(bb & ((1ull << lane) - 1ull));
    if (nz) {
      float w = wrow[c * 64 + lane] * m;
      int wi = __float2int_rn(w * 8388608.f);  // 2^23
      wi = wi > 2097151 ? 2097151 : (wi < -2097151 ? -2097151 : wi);
      if (pos < 128u) csr[((size_t)r << 7) + pos] = (((unsigned)wi) << 10) | (unsigned)(c * 64 + lane);
    }
    cnt += (unsigned)__popcll(bb);
  }
  for (unsigned p = (cnt > 128u ? 128u : cnt) + (unsigned)lane; p < 128u; p += 64u)
    csr[((size_t)r << 7) + p] = (p & 63u);  // w=0 pad, lane-matched target (conflict-free)
  if (lane == 0) rowhi[r] = (cnt > 64u) ? 1u : 0u;
}

// ---------------- Wt2 [1024][2048] bf16: k2 = 4*i + c, c in {0,1}->hi, {2,3}->lo --------------
__global__ void k_build_wt(const float* __restrict__ W_in, unsigned short* __restrict__ Wt) {
  int n = blockIdx.y;
  int k2 = blockIdx.x * 256 + threadIdx.x;
  int i = k2 >> 2;
  float w = W_in[i * H_ + n];
  unsigned short hi = bf16_rne(w);
  unsigned short v = (k2 & 2) ? bf16_rne(w - bf16_to_f(hi)) : hi;
  Wt[(size_t)n * 2048 + k2] = v;
}

// ---------------- xs2 chunk [128*Tc][2048] bf16: 4 bf16 per f32: {hi,lo,hi,lo} ----------------
__global__ void k_build_xs(const float* __restrict__ x, unsigned short* __restrict__ xs,
                           int t0, int Tc) {
  int id = blockIdx.x * 256 + threadIdx.x;
  int rr = id >> 7;
  int q = id & 127;
  int b = rr / Tc, tt = rr % Tc;
  const float4 v = *(const float4*)&x[((size_t)(b * T_ + t0 + tt)) * I_ + q * 4];
  alignas(16) unsigned short o[16];
  float vv[4] = {v.x, v.y, v.z, v.w};
#pragma unroll
  for (int j = 0; j < 4; ++j) {
    unsigned short hi = bf16_rne(vv[j]);
    unsigned short lo = bf16_rne(vv[j] - bf16_to_f(hi));
    o[4 * j + 0] = hi; o[4 * j + 1] = lo; o[4 * j + 2] = hi; o[4 * j + 3] = lo;
  }
  *(u32x4*)&xs[(size_t)rr * 2048 + q * 16] = *(u32x4*)o;
  *(u32x4*)&xs[(size_t)rr * 2048 + q * 16 + 8] = *(u32x4*)(o + 8);
}

// ---------------- split-bf16 GEMM (unchanged): drive[rr][h] ----------------------------------
#define LDA 72
__global__ __launch_bounds__(512, 1) void k_gemm(const unsigned short* __restrict__ xs,
                                                 const unsigned short* __restrict__ Wt,
                                                 float* __restrict__ drive) {
  __shared__ __align__(16) unsigned short As[128 * LDA];
  __shared__ __align__(16) unsigned short Bs[256 * LDA];
  int mt = blockIdx.x, nt = blockIdx.y;
  int tid = threadIdx.x;
  int lane = tid & 63, w = tid >> 6;
  int wr = w >> 2, wc = w & 3;
  f32x4 acc[4][4] = {};
  int arow = tid >> 2, aq = tid & 3;
  int brow = tid >> 1, bh = tid & 1;
  const unsigned short* xsrow = xs + (size_t)(mt * 128 + arow) * 2048 + aq * 16;
  const unsigned short* wtrow = Wt + (size_t)(nt * 256 + brow) * 2048 + bh * 32;
  for (int kt = 0; kt < 32; ++kt) {
    u32x4 a0 = *(const u32x4*)(xsrow + kt * 64);
    u32x4 a1 = *(const u32x4*)(xsrow + kt * 64 + 8);
    u32x4 b0 = *(const u32x4*)(wtrow + kt * 64);
    u32x4 b1 = *(const u32x4*)(wtrow + kt * 64 + 8);
    u32x4 b2 = *(const u32x4*)(wtrow + kt * 64 + 16);
    u32x4 b3 = *(const u32x4*)(wtrow + kt * 64 + 24);
    __syncthreads();
    *(u32x4*)&As[arow * LDA + aq * 16] = a0;
    *(u32x4*)&As[arow * LDA + aq * 16 + 8] = a1;
    *(u32x4*)&Bs[brow * LDA + bh * 32] = b0;
    *(u32x4*)&Bs[brow * LDA + bh * 32 + 8] = b1;
    *(u32x4*)&Bs[brow * LDA + bh * 32 + 16] = b2;
    *(u32x4*)&Bs[brow * LDA + bh * 32 + 24] = b3;
    __syncthreads();
#pragma unroll
    for (int kk = 0; kk < 2; ++kk) {
      bf16x8 af[4], bf[4];
#pragma unroll
      for (int mi = 0; mi < 4; ++mi)
        af[mi] = *(const bf16x8*)&As[(wr * 64 + mi * 16 + (lane & 15)) * LDA + kk * 32 + (lane >> 4) * 8];
#pragma unroll
      for (int ni = 0; ni < 4; ++ni)
        bf[ni] = *(const bf16x8*)&Bs[(wc * 64 + ni * 16 + (lane & 15)) * LDA + kk * 32 + (lane >> 4) * 8];
#pragma unroll
      for (int mi = 0; mi < 4; ++mi)
#pragma unroll
        for (int ni = 0; ni < 4; ++ni)
          acc[mi][ni] = __builtin_amdgcn_mfma_f32_16x16x32_bf16(af[mi], bf[ni], acc[mi][ni], 0, 0, 0);
    }
  }
  int r0 = (lane >> 4) * 4, c0 = lane & 15;
#pragma unroll
  for (int mi = 0; mi < 4; ++mi) {
    int rowb = mt * 128 + wr * 64 + mi * 16 + r0;
#pragma unroll
    for (int ni = 0; ni < 4; ++ni) {
      int col = nt * 256 + wc * 64 + ni * 16 + c0;
#pragma unroll
      for (int r = 0; r < 4; ++r)
        drive[(size_t)(rowb + r) * H_ + col] = acc[mi][ni][r];
    }
  }
}

// ---------------- recurrent scan: event-driven scatter, integer LDS accumulation --------------
__global__ __launch_bounds__(1024, 1) void k_rsnn(
    const float* __restrict__ drive, const unsigned int* __restrict__ csr,
    const unsigned int* __restrict__ rowhi,
    const float* __restrict__ h_bias, const float* __restrict__ W_out,
    const float* __restrict__ b_out,
    float* __restrict__ state_v, float* __restrict__ state_s, float* __restrict__ state_c,
    float* __restrict__ out, int t0, int Tc, int last) {
  __shared__ int accL[H_];
  __shared__ unsigned int listL[H_];
  __shared__ unsigned int fcL[2];
  __shared__ float red[H_];
  __shared__ float part[352];
  int tid = threadIdx.x;
  int b = blockIdx.x;
  int lane = tid & 63;
  float bias = h_bias[tid];
  unsigned myhi = rowhi[tid] << 12;
  float v, s, cnt;
  if (t0 == 0) { v = 0.f; s = 0.f; cnt = 0.f; }
  else { v = state_v[b * H_ + tid]; s = state_s[b * H_ + tid]; cnt = state_c[b * H_ + tid]; }
  accL[tid] = 0;
  if (tid < 2) fcL[tid] = 0;
  __syncthreads();
  {  // initial firing list from carried state
    bool f0 = s > 0.f;
    unsigned long long bb = __ballot(f0);
    unsigned n = (unsigned)__popcll(bb);
    unsigned pos = (unsigned)__popcll(bb & ((1ull << lane) - 1ull));
    unsigned wb = 0;
    if (lane == 0) wb = atomicAdd(&fcL[0], n);
    wb = __shfl(wb, 0, 64);
    if (f0) listL[wb + pos] = (unsigned)tid | myhi;
  }
  __syncthreads();
  const float* dptr = drive + (size_t)b * Tc * H_ + tid;
  int wv = tid >> 6;
  float dcur = dptr[0];
  for (int t = 0; t < Tc; ++t) {
    float dnxt = (t + 1 < Tc) ? dptr[(size_t)(t + 1) * H_] : 0.f;
    unsigned F = fcL[t & 1];
    // -------- scatter: wave wv owns slots idx == wv (mod 16); 16-slot flight batches --------
    for (unsigned i0 = (unsigned)wv; i0 < F; i0 += 256u) {
      unsigned ents[16], es[16], es2[16];
#pragma unroll
      for (int u = 0; u < 16; ++u) {
        unsigned idx = i0 + (unsigned)u * 16u;
        ents[u] = (idx < F) ? listL[idx] : 0xFFFFFFFFu;
      }
#pragma unroll
      for (int u = 0; u < 16; ++u) {
        if (ents[u] != 0xFFFFFFFFu) {
          const unsigned int* row = csr + ((size_t)(ents[u] & 1023u) << 7);
          es[u] = row[lane];
          if (ents[u] & 4096u) es2[u] = row[64 + lane];
        }
      }
#pragma unroll
      for (int u = 0; u < 16; ++u) {
        if (ents[u] != 0xFFFFFFFFu) {
          atomicAdd(&accL[es[u] & 1023u], ((int)es[u]) >> 10);
          if (ents[u] & 4096u) atomicAdd(&accL[es2[u] & 1023u], ((int)es2[u]) >> 10);
        }
      }
    }
    __syncthreads();
    // -------- membrane update + next firing list --------
    int ri = accL[tid];
    accL[tid] = 0;
    float rec = (float)ri * 1.1920929e-7f;  // 2^-23
    v = BETA * v + (dcur + bias) + rec;
    bool f = v > THRESH;
    v -= f ? THRESH : 0.f;
    cnt += f ? 1.f : 0.f;
    s = f ? 1.f : 0.f;
    unsigned long long bb = __ballot(f);
    unsigned n = (unsigned)__popcll(bb);
    unsigned pos = (unsigned)__popcll(bb & ((1ull << lane) - 1ull));
    unsigned wb = 0;
    if (lane == 0) wb = atomicAdd(&fcL[(t + 1) & 1], n);
    wb = __shfl(wb, 0, 64);
    if (f) listL[wb + pos] = (unsigned)tid | myhi;
    if (tid == 0) fcL[t & 1] = 0;
    dcur = dnxt;
    __syncthreads();
  }
  if (!last) {
    state_v[b * H_ + tid] = v; state_s[b * H_ + tid] = s; state_c[b * H_ + tid] = cnt;
  } else {
    red[tid] = cnt;
    __syncthreads();
    if (tid < 352) {
      int o = tid >> 5, seg = tid & 31;
      float p = 0.f;
      for (int j = 0; j < 32; ++j) {
        int hh = seg * 32 + j;
        p += red[hh] * W_out[hh * O_ + o];
      }
      part[tid] = p;
    }
    __syncthreads();
    if (tid < O_) {
      float sum = 0.f;
      for (int g = 0; g < 32; ++g) sum += part[(tid << 5) + g];
      out[b * O_ + tid] = b_out[tid] + sum * (1.0f / (float)T_);
    }
  }
}

extern "C" void kernel_launch(void* const* d_in, const int* in_sizes, int n_in,
                              void* d_out, int out_size, void* d_ws, size_t ws_size,
                              hipStream_t stream) {
  (void)in_sizes; (void)n_in; (void)out_size;
  const float* x = (const float*)d_in[0];
  const float* W_in = (const float*)d_in[1];
  const float* W_rec = (const float*)d_in[2];
  const float* W_out = (const float*)d_in[3];
  const float* h_bias = (const float*)d_in[4];
  const float* b_out = (const float*)d_in[5];
  const float* mask = (const float*)d_in[6];
  float* out = (float*)d_out;

  char* ws = (char*)d_ws;
  size_t off = 0;
  auto alloc = [&](size_t bytes) {
    void* p = ws + off;
    off = (off + bytes + 255) & ~(size_t)255;
    return p;
  };
  unsigned short* Wt = (unsigned short*)alloc((size_t)H_ * 2048 * 2);
  unsigned int* csr = (unsigned int*)alloc((size_t)H_ * 128 * 4);
  unsigned int* rowhi = (unsigned int*)alloc((size_t)H_ * 4);
  float* st_v = (float*)alloc((size_t)B_ * H_ * 4);
  float* st_s = (float*)alloc((size_t)B_ * H_ * 4);
  float* st_c = (float*)alloc((size_t)B_ * H_ * 4);
  size_t fixed = off;

  size_t per_t = (size_t)128 * 2048 * 2 + (size_t)128 * 1024 * 4;
  int Tc = 1;
  if (ws_size > fixed + per_t) Tc = (int)((ws_size - fixed) / per_t);
  if (Tc > T_) Tc = T_;
  if (Tc < 1) Tc = 1;
  unsigned short* xs = (unsigned short*)alloc((size_t)128 * Tc * 2048 * 2);
  float* drive = (float*)alloc((size_t)128 * Tc * 1024 * 4);

  k_csr<<<dim3(256), dim3(256), 0, stream>>>(W_rec, mask, csr, rowhi);
  k_build_wt<<<dim3(8, 1024), dim3(256), 0, stream>>>(W_in, Wt);

  for (int t0 = 0; t0 < T_; t0 += Tc) {
    int tc = (Tc < T_ - t0) ? Tc : (T_ - t0);
    k_build_xs<<<dim3(64 * tc), dim3(256), 0, stream>>>(x, xs, t0, tc);
    k_gemm<<<dim3(tc, 4), dim3(512), 0, stream>>>(xs, Wt, drive);
    k_rsnn<<<dim3(128), dim3(1024), 0, stream>>>(drive, csr, rowhi, h_bias, W_out, b_out,
                                                 st_v, st_s, st_c, out, t0, tc,
                                                 (t0 + tc >= T_) ? 1 : 0);
  }
}

// Round 5
// 1177.157 us; speedup vs baseline: 2.4548x; 1.2458x over previous
//
#include <hip/hip_runtime.h>
#include <cstdint>
#include <cstddef>

#define B_ 128
#define T_ 500
#define I_ 512
#define H_ 1024
#define O_ 11
#define BETA 0.9f
#define THRESH 1.0f
#define K2_ 1536  // 3-term split: xh*wh + xl*wh + xh*wl

typedef __attribute__((ext_vector_type(4))) float f32x4;
typedef __attribute__((ext_vector_type(8))) short bf16x8;
typedef __attribute__((ext_vector_type(4))) unsigned int u32x4;

__device__ __forceinline__ unsigned short bf16_rne(float f) {
  unsigned int u = __float_as_uint(f);
  unsigned int r = u + 0x7FFFu + ((u >> 16) & 1u);
  return (unsigned short)(r >> 16);
}
__device__ __forceinline__ float bf16_to_f(unsigned short h) {
  return __uint_as_float(((unsigned int)h) << 16);
}

// ---------------- CSR build: row r = outgoing edges of neuron r, 128 slots -------------------
// entry = (w22 << 10) | target10, w22 = round(W_eff * 2^23) clamped; pad: w=0, tgt=(slot&63)
__global__ void k_csr(const float* __restrict__ W_rec, const float* __restrict__ mask,
                      unsigned int* __restrict__ csr, unsigned int* __restrict__ rowhi) {
  int r = blockIdx.x * 4 + (threadIdx.x >> 6);  // one wave per row
  int lane = threadIdx.x & 63;
  const float* mrow = mask + (size_t)r * H_;
  const float* wrow = W_rec + (size_t)r * H_;
  unsigned cnt = 0;
  for (int c = 0; c < 16; ++c) {
    float m = mrow[c * 64 + lane];
    bool nz = (m != 0.f);
    unsigned long long bb = __ballot(nz);
    unsigned pos = cnt + (unsigned)__popcll(bb & ((1ull << lane) - 1ull));
    if (nz) {
      float w = wrow[c * 64 + lane] * m;
      int wi = __float2int_rn(w * 8388608.f);  // 2^23
      wi = wi > 2097151 ? 2097151 : (wi < -2097151 ? -2097151 : wi);
      if (pos < 128u) csr[((size_t)r << 7) + pos] = (((unsigned)wi) << 10) | (unsigned)(c * 64 + lane);
    }
    cnt += (unsigned)__popcll(bb);
  }
  for (unsigned p = (cnt > 128u ? 128u : cnt) + (unsigned)lane; p < 128u; p += 64u)
    csr[((size_t)r << 7) + p] = (p & 63u);  // w=0 pad, lane-matched target (conflict-free)
  if (lane == 0) rowhi[r] = (cnt > 64u) ? 1u : 0u;
}

// ---------------- Wt [1024][1536] bf16: k2 = 3*i + c; c: 0->wh, 1->wh, 2->wl ------------------
__global__ void k_build_wt(const float* __restrict__ W_in, unsigned short* __restrict__ Wt) {
  int n = blockIdx.y;
  int k2 = blockIdx.x * 256 + threadIdx.x;  // 0..1535
  int i = k2 / 3;
  int c = k2 - 3 * i;
  float w = W_in[i * H_ + n];
  unsigned short hi = bf16_rne(w);
  unsigned short v = (c == 2) ? bf16_rne(w - bf16_to_f(hi)) : hi;
  Wt[(size_t)n * K2_ + k2] = v;
}

// ---------------- xs chunk [128*Tc][1536] bf16: per f32 j -> {xh, xl, xh} ---------------------
__global__ void k_build_xs(const float* __restrict__ x, unsigned short* __restrict__ xs,
                           int t0, int Tc) {
  int id = blockIdx.x * 256 + threadIdx.x;  // one thread = 8 consecutive f32 -> 24 bf16 (48B)
  int rr = id >> 6;                          // 64 octs per row (512/8)
  int oct = id & 63;
  int b = rr / Tc, tt = rr % Tc;
  const float4 v0 = *(const float4*)&x[((size_t)(b * T_ + t0 + tt)) * I_ + oct * 8];
  const float4 v1 = *(const float4*)&x[((size_t)(b * T_ + t0 + tt)) * I_ + oct * 8 + 4];
  alignas(16) unsigned short o[24];
  float vv[8] = {v0.x, v0.y, v0.z, v0.w, v1.x, v1.y, v1.z, v1.w};
#pragma unroll
  for (int j = 0; j < 8; ++j) {
    unsigned short hi = bf16_rne(vv[j]);
    unsigned short lo = bf16_rne(vv[j] - bf16_to_f(hi));
    o[3 * j + 0] = hi; o[3 * j + 1] = lo; o[3 * j + 2] = hi;
  }
  unsigned short* dst = xs + (size_t)rr * K2_ + oct * 24;
  *(u32x4*)(dst + 0) = *(u32x4*)(o + 0);
  *(u32x4*)(dst + 8) = *(u32x4*)(o + 8);
  *(u32x4*)(dst + 16) = *(u32x4*)(o + 16);
}

// ---------------- split-bf16 GEMM: drive[rr][h], K2=1536 --------------------------------------
#define LDA 72
__global__ __launch_bounds__(512, 1) void k_gemm(const unsigned short* __restrict__ xs,
                                                 const unsigned short* __restrict__ Wt,
                                                 float* __restrict__ drive) {
  __shared__ __align__(16) unsigned short As[128 * LDA];
  __shared__ __align__(16) unsigned short Bs[256 * LDA];
  int mt = blockIdx.x, nt = blockIdx.y;
  int tid = threadIdx.x;
  int lane = tid & 63, w = tid >> 6;
  int wr = w >> 2, wc = w & 3;
  f32x4 acc[4][4] = {};
  int arow = tid >> 2, aq = tid & 3;
  int brow = tid >> 1, bh = tid & 1;
  const unsigned short* xsrow = xs + (size_t)(mt * 128 + arow) * K2_ + aq * 16;
  const unsigned short* wtrow = Wt + (size_t)(nt * 256 + brow) * K2_ + bh * 32;
  for (int kt = 0; kt < K2_ / 64; ++kt) {
    u32x4 a0 = *(const u32x4*)(xsrow + kt * 64);
    u32x4 a1 = *(const u32x4*)(xsrow + kt * 64 + 8);
    u32x4 b0 = *(const u32x4*)(wtrow + kt * 64);
    u32x4 b1 = *(const u32x4*)(wtrow + kt * 64 + 8);
    u32x4 b2 = *(const u32x4*)(wtrow + kt * 64 + 16);
    u32x4 b3 = *(const u32x4*)(wtrow + kt * 64 + 24);
    __syncthreads();
    *(u32x4*)&As[arow * LDA + aq * 16] = a0;
    *(u32x4*)&As[arow * LDA + aq * 16 + 8] = a1;
    *(u32x4*)&Bs[brow * LDA + bh * 32] = b0;
    *(u32x4*)&Bs[brow * LDA + bh * 32 + 8] = b1;
    *(u32x4*)&Bs[brow * LDA + bh * 32 + 16] = b2;
    *(u32x4*)&Bs[brow * LDA + bh * 32 + 24] = b3;
    __syncthreads();
#pragma unroll
    for (int kk = 0; kk < 2; ++kk) {
      bf16x8 af[4], bf[4];
#pragma unroll
      for (int mi = 0; mi < 4; ++mi)
        af[mi] = *(const bf16x8*)&As[(wr * 64 + mi * 16 + (lane & 15)) * LDA + kk * 32 + (lane >> 4) * 8];
#pragma unroll
      for (int ni = 0; ni < 4; ++ni)
        bf[ni] = *(const bf16x8*)&Bs[(wc * 64 + ni * 16 + (lane & 15)) * LDA + kk * 32 + (lane >> 4) * 8];
#pragma unroll
      for (int mi = 0; mi < 4; ++mi)
#pragma unroll
        for (int ni = 0; ni < 4; ++ni)
          acc[mi][ni] = __builtin_amdgcn_mfma_f32_16x16x32_bf16(af[mi], bf[ni], acc[mi][ni], 0, 0, 0);
    }
  }
  int r0 = (lane >> 4) * 4, c0 = lane & 15;
#pragma unroll
  for (int mi = 0; mi < 4; ++mi) {
    int rowb = mt * 128 + wr * 64 + mi * 16 + r0;
#pragma unroll
    for (int ni = 0; ni < 4; ++ni) {
      int col = nt * 256 + wc * 64 + ni * 16 + c0;
#pragma unroll
      for (int r = 0; r < 4; ++r)
        drive[(size_t)(rowb + r) * H_ + col] = acc[mi][ni][r];
    }
  }
}

// ---------------- recurrent scan: event-driven scatter, contiguous chunks + readlane ----------
__global__ __launch_bounds__(1024, 1) void k_rsnn(
    const float* __restrict__ drive, const unsigned int* __restrict__ csr,
    const unsigned int* __restrict__ rowhi,
    const float* __restrict__ h_bias, const float* __restrict__ W_out,
    const float* __restrict__ b_out,
    float* __restrict__ state_v, float* __restrict__ state_s, float* __restrict__ state_c,
    float* __restrict__ out, int t0, int Tc, int last) {
  __shared__ int accL[H_];
  __shared__ unsigned int listL[H_];
  __shared__ unsigned int fcL[2];
  __shared__ float red[H_];
  __shared__ float part[352];
  int tid = threadIdx.x;
  int b = blockIdx.x;
  int lane = tid & 63;
  int wv = tid >> 6;
  float bias = h_bias[tid];
  unsigned myhi = rowhi[tid] << 12;
  float v, s, cnt;
  if (t0 == 0) { v = 0.f; s = 0.f; cnt = 0.f; }
  else { v = state_v[b * H_ + tid]; s = state_s[b * H_ + tid]; cnt = state_c[b * H_ + tid]; }
  accL[tid] = 0;
  if (tid < 2) fcL[tid] = 0;
  __syncthreads();
  {  // initial firing list from carried state
    bool f0 = s > 0.f;
    unsigned long long bb = __ballot(f0);
    unsigned n = (unsigned)__popcll(bb);
    unsigned pos = (unsigned)__popcll(bb & ((1ull << lane) - 1ull));
    unsigned wb = 0;
    if (lane == 0) wb = atomicAdd(&fcL[0], n);
    wb = (unsigned)__builtin_amdgcn_readfirstlane((int)wb);
    if (f0) listL[wb + pos] = (unsigned)tid | myhi;
  }
  __syncthreads();
  const float* dptr = drive + (size_t)b * Tc * H_ + tid;
  float dcur = dptr[0];
  for (int t = 0; t < Tc; ++t) {
    float dnxt = (t + 1 < Tc) ? dptr[(size_t)(t + 1) * H_] : 0.f;
    unsigned F = fcL[t & 1];
    // wave wv owns contiguous slots [F*wv/16, F*(wv+1)/16)
    unsigned lo = (F * (unsigned)wv) >> 4;
    unsigned hi = (F * ((unsigned)wv + 1)) >> 4;
    for (unsigned i0 = lo; i0 < hi; i0 += 16u) {
      unsigned idx = i0 + ((unsigned)lane & 15u);
      unsigned ents = listL[idx < hi ? idx : (hi - 1u)];  // ONE ds_read per 16 slots
      unsigned n16 = hi - i0; n16 = n16 < 16u ? n16 : 16u; // wave-uniform
      unsigned e[16], es[16], es2[16];
#pragma unroll
      for (int u = 0; u < 16; ++u) e[u] = (unsigned)__builtin_amdgcn_readlane((int)ents, u);
#pragma unroll
      for (int u = 0; u < 16; ++u) {
        if ((unsigned)u < n16) {  // uniform branch (SGPR)
          const unsigned int* row = csr + ((size_t)(e[u] & 1023u) << 7);
          es[u] = row[lane];
          if (e[u] & 4096u) es2[u] = row[64 + lane];
        }
      }
#pragma unroll
      for (int u = 0; u < 16; ++u) {
        if ((unsigned)u < n16) {
          atomicAdd(&accL[es[u] & 1023u], ((int)es[u]) >> 10);
          if (e[u] & 4096u) atomicAdd(&accL[es2[u] & 1023u], ((int)es2[u]) >> 10);
        }
      }
    }
    __syncthreads();
    // -------- membrane update + next firing list --------
    int ri = accL[tid];
    accL[tid] = 0;
    float rec = (float)ri * 1.1920929e-7f;  // 2^-23
    v = BETA * v + (dcur + bias) + rec;
    bool f = v > THRESH;
    v -= f ? THRESH : 0.f;
    cnt += f ? 1.f : 0.f;
    s = f ? 1.f : 0.f;
    unsigned long long bb = __ballot(f);
    unsigned n = (unsigned)__popcll(bb);
    unsigned pos = (unsigned)__popcll(bb & ((1ull << lane) - 1ull));
    unsigned wb = 0;
    if (lane == 0) wb = atomicAdd(&fcL[(t + 1) & 1], n);
    wb = (unsigned)__builtin_amdgcn_readfirstlane((int)wb);
    if (f) listL[wb + pos] = (unsigned)tid | myhi;
    if (tid == 0) fcL[t & 1] = 0;
    dcur = dnxt;
    __syncthreads();
  }
  if (!last) {
    state_v[b * H_ + tid] = v; state_s[b * H_ + tid] = s; state_c[b * H_ + tid] = cnt;
  } else {
    red[tid] = cnt;
    __syncthreads();
    if (tid < 352) {
      int o = tid >> 5, seg = tid & 31;
      float p = 0.f;
      for (int j = 0; j < 32; ++j) {
        int hh = seg * 32 + j;
        p += red[hh] * W_out[hh * O_ + o];
      }
      part[tid] = p;
    }
    __syncthreads();
    if (tid < O_) {
      float sum = 0.f;
      for (int g = 0; g < 32; ++g) sum += part[(tid << 5) + g];
      out[b * O_ + tid] = b_out[tid] + sum * (1.0f / (float)T_);
    }
  }
}

extern "C" void kernel_launch(void* const* d_in, const int* in_sizes, int n_in,
                              void* d_out, int out_size, void* d_ws, size_t ws_size,
                              hipStream_t stream) {
  (void)in_sizes; (void)n_in; (void)out_size;
  const float* x = (const float*)d_in[0];
  const float* W_in = (const float*)d_in[1];
  const float* W_rec = (const float*)d_in[2];
  const float* W_out = (const float*)d_in[3];
  const float* h_bias = (const float*)d_in[4];
  const float* b_out = (const float*)d_in[5];
  const float* mask = (const float*)d_in[6];
  float* out = (float*)d_out;

  char* ws = (char*)d_ws;
  size_t off = 0;
  auto alloc = [&](size_t bytes) {
    void* p = ws + off;
    off = (off + bytes + 255) & ~(size_t)255;
    return p;
  };
  unsigned short* Wt = (unsigned short*)alloc((size_t)H_ * K2_ * 2);
  unsigned int* csr = (unsigned int*)alloc((size_t)H_ * 128 * 4);
  unsigned int* rowhi = (unsigned int*)alloc((size_t)H_ * 4);
  float* st_v = (float*)alloc((size_t)B_ * H_ * 4);
  float* st_s = (float*)alloc((size_t)B_ * H_ * 4);
  float* st_c = (float*)alloc((size_t)B_ * H_ * 4);
  size_t fixed = off;

  size_t per_t = (size_t)128 * K2_ * 2 + (size_t)128 * 1024 * 4;
  int Tc = 1;
  if (ws_size > fixed + per_t) Tc = (int)((ws_size - fixed) / per_t);
  if (Tc > T_) Tc = T_;
  if (Tc < 1) Tc = 1;
  unsigned short* xs = (unsigned short*)alloc((size_t)128 * Tc * K2_ * 2);
  float* drive = (float*)alloc((size_t)128 * Tc * 1024 * 4);

  k_csr<<<dim3(256), dim3(256), 0, stream>>>(W_rec, mask, csr, rowhi);
  k_build_wt<<<dim3(6, 1024), dim3(256), 0, stream>>>(W_in, Wt);

  for (int t0 = 0; t0 < T_; t0 += Tc) {
    int tc = (Tc < T_ - t0) ? Tc : (T_ - t0);
    k_build_xs<<<dim3(32 * tc), dim3(256), 0, stream>>>(x, xs, t0, tc);
    k_gemm<<<dim3(tc, 4), dim3(512), 0, stream>>>(xs, Wt, drive);
    k_rsnn<<<dim3(128), dim3(1024), 0, stream>>>(drive, csr, rowhi, h_bias, W_out, b_out,
                                                 st_v, st_s, st_c, out, t0, tc,
                                                 (t0 + tc >= T_) ? 1 : 0);
  }
}

// Round 7
// 1081.872 us; speedup vs baseline: 2.6710x; 1.0881x over previous
//
#include <hip/hip_runtime.h>
#include <cstdint>
#include <cstddef>

#define B_ 128
#define T_ 500
#define I_ 512
#define H_ 1024
#define O_ 11
#define BETA 0.9f
#define THRESH 1.0f
#define K2_ 1536  // 3-term split: xh*wh + xl*wh + xh*wl

typedef __attribute__((ext_vector_type(4))) float f32x4;
typedef __attribute__((ext_vector_type(8))) short bf16x8;
typedef __attribute__((ext_vector_type(4))) unsigned int u32x4;

__device__ __forceinline__ unsigned short bf16_rne(float f) {
  unsigned int u = __float_as_uint(f);
  unsigned int r = u + 0x7FFFu + ((u >> 16) & 1u);
  return (unsigned short)(r >> 16);
}
__device__ __forceinline__ float bf16_to_f(unsigned short h) {
  return __uint_as_float(((unsigned int)h) << 16);
}

// ---------------- CSR build: row r = outgoing edges of neuron r, 128 slots -------------------
// entry = (w22 << 10) | target10; pad: w=0, tgt=(slot&63). Row 1024 = all-pad dummy row.
__global__ void k_csr(const float* __restrict__ W_rec, const float* __restrict__ mask,
                      unsigned int* __restrict__ csr, unsigned int* __restrict__ rowhi) {
  int r = blockIdx.x * 4 + (threadIdx.x >> 6);  // one wave per row
  if (r > 1024) return;
  int lane = threadIdx.x & 63;
  unsigned cnt = 0;
  if (r < 1024) {
    const float* mrow = mask + (size_t)r * H_;
    const float* wrow = W_rec + (size_t)r * H_;
    for (int c = 0; c < 16; ++c) {
      float m = mrow[c * 64 + lane];
      bool nz = (m != 0.f);
      unsigned long long bb = __ballot(nz);
      unsigned pos = cnt + (unsigned)__popcll(bb & ((1ull << lane) - 1ull));
      if (nz) {
        float w = wrow[c * 64 + lane] * m;
        int wi = __float2int_rn(w * 8388608.f);  // 2^23
        wi = wi > 2097151 ? 2097151 : (wi < -2097151 ? -2097151 : wi);
        if (pos < 128u) csr[((size_t)r << 7) + pos] = (((unsigned)wi) << 10) | (unsigned)(c * 64 + lane);
      }
      cnt += (unsigned)__popcll(bb);
    }
  }
  for (unsigned p = (cnt > 128u ? 128u : cnt) + (unsigned)lane; p < 128u; p += 64u)
    csr[((size_t)r << 7) + p] = (p & 63u);  // w=0 pad, lane-matched target (conflict-free)
  if (lane == 0) rowhi[r] = (cnt > 64u) ? 1u : 0u;
}

// ---------------- Wt [1024][1536] bf16: k2 = 3*i + c; c: 0->wh, 1->wh, 2->wl ------------------
__global__ void k_build_wt(const float* __restrict__ W_in, unsigned short* __restrict__ Wt) {
  int n = blockIdx.y;
  int k2 = blockIdx.x * 256 + threadIdx.x;  // 0..1535
  int i = k2 / 3;
  int c = k2 - 3 * i;
  float w = W_in[i * H_ + n];
  unsigned short hi = bf16_rne(w);
  unsigned short v = (c == 2) ? bf16_rne(w - bf16_to_f(hi)) : hi;
  Wt[(size_t)n * K2_ + k2] = v;
}

// ---------------- xs chunk [128*Tc][1536] bf16: per f32 j -> {xh, xl, xh} ---------------------
__global__ void k_build_xs(const float* __restrict__ x, unsigned short* __restrict__ xs,
                           int t0, int Tc) {
  int id = blockIdx.x * 256 + threadIdx.x;  // one thread = 8 consecutive f32 -> 24 bf16 (48B)
  int rr = id >> 6;                          // 64 octs per row (512/8)
  int oct = id & 63;
  int b = rr / Tc, tt = rr % Tc;
  const float4 v0 = *(const float4*)&x[((size_t)(b * T_ + t0 + tt)) * I_ + oct * 8];
  const float4 v1 = *(const float4*)&x[((size_t)(b * T_ + t0 + tt)) * I_ + oct * 8 + 4];
  alignas(16) unsigned short o[24];
  float vv[8] = {v0.x, v0.y, v0.z, v0.w, v1.x, v1.y, v1.z, v1.w};
#pragma unroll
  for (int j = 0; j < 8; ++j) {
    unsigned short hi = bf16_rne(vv[j]);
    unsigned short lo = bf16_rne(vv[j] - bf16_to_f(hi));
    o[3 * j + 0] = hi; o[3 * j + 1] = lo; o[3 * j + 2] = hi;
  }
  unsigned short* dst = xs + (size_t)rr * K2_ + oct * 24;
  *(u32x4*)(dst + 0) = *(u32x4*)(o + 0);
  *(u32x4*)(dst + 8) = *(u32x4*)(o + 8);
  *(u32x4*)(dst + 16) = *(u32x4*)(o + 16);
}

// ---------------- split-bf16 GEMM: drive[rr][h], K2=1536 --------------------------------------
#define LDA 72
__global__ __launch_bounds__(512, 1) void k_gemm(const unsigned short* __restrict__ xs,
                                                 const unsigned short* __restrict__ Wt,
                                                 float* __restrict__ drive) {
  __shared__ __align__(16) unsigned short As[128 * LDA];
  __shared__ __align__(16) unsigned short Bs[256 * LDA];
  int mt = blockIdx.x, nt = blockIdx.y;
  int tid = threadIdx.x;
  int lane = tid & 63, w = tid >> 6;
  int wr = w >> 2, wc = w & 3;
  f32x4 acc[4][4] = {};
  int arow = tid >> 2, aq = tid & 3;
  int brow = tid >> 1, bh = tid & 1;
  const unsigned short* xsrow = xs + (size_t)(mt * 128 + arow) * K2_ + aq * 16;
  const unsigned short* wtrow = Wt + (size_t)(nt * 256 + brow) * K2_ + bh * 32;
  for (int kt = 0; kt < K2_ / 64; ++kt) {
    u32x4 a0 = *(const u32x4*)(xsrow + kt * 64);
    u32x4 a1 = *(const u32x4*)(xsrow + kt * 64 + 8);
    u32x4 b0 = *(const u32x4*)(wtrow + kt * 64);
    u32x4 b1 = *(const u32x4*)(wtrow + kt * 64 + 8);
    u32x4 b2 = *(const u32x4*)(wtrow + kt * 64 + 16);
    u32x4 b3 = *(const u32x4*)(wtrow + kt * 64 + 24);
    __syncthreads();
    *(u32x4*)&As[arow * LDA + aq * 16] = a0;
    *(u32x4*)&As[arow * LDA + aq * 16 + 8] = a1;
    *(u32x4*)&Bs[brow * LDA + bh * 32] = b0;
    *(u32x4*)&Bs[brow * LDA + bh * 32 + 8] = b1;
    *(u32x4*)&Bs[brow * LDA + bh * 32 + 16] = b2;
    *(u32x4*)&Bs[brow * LDA + bh * 32 + 24] = b3;
    __syncthreads();
#pragma unroll
    for (int kk = 0; kk < 2; ++kk) {
      bf16x8 af[4], bf[4];
#pragma unroll
      for (int mi = 0; mi < 4; ++mi)
        af[mi] = *(const bf16x8*)&As[(wr * 64 + mi * 16 + (lane & 15)) * LDA + kk * 32 + (lane >> 4) * 8];
#pragma unroll
      for (int ni = 0; ni < 4; ++ni)
        bf[ni] = *(const bf16x8*)&Bs[(wc * 64 + ni * 16 + (lane & 15)) * LDA + kk * 32 + (lane >> 4) * 8];
#pragma unroll
      for (int mi = 0; mi < 4; ++mi)
#pragma unroll
        for (int ni = 0; ni < 4; ++ni)
          acc[mi][ni] = __builtin_amdgcn_mfma_f32_16x16x32_bf16(af[mi], bf[ni], acc[mi][ni], 0, 0, 0);
    }
  }
  int r0 = (lane >> 4) * 4, c0 = lane & 15;
#pragma unroll
  for (int mi = 0; mi < 4; ++mi) {
    int rowb = mt * 128 + wr * 64 + mi * 16 + r0;
#pragma unroll
    for (int ni = 0; ni < 4; ++ni) {
      int col = nt * 256 + wc * 64 + ni * 16 + c0;
#pragma unroll
      for (int r = 0; r < 4; ++r)
        drive[(size_t)(rowb + r) * H_ + col] = acc[mi][ni][r];
    }
  }
}

// ---------------- recurrent scan: event scatter, named-register 8-slot batches ----------------
__global__ __launch_bounds__(1024, 1) void k_rsnn(
    const float* __restrict__ drive, const unsigned int* __restrict__ csr,
    const unsigned int* __restrict__ rowhi,
    const float* __restrict__ h_bias, const float* __restrict__ W_out,
    const float* __restrict__ b_out,
    float* __restrict__ state_v, float* __restrict__ state_s, float* __restrict__ state_c,
    float* __restrict__ out, int t0, int Tc, int last) {
  __shared__ int accL[H_];
  __shared__ unsigned int listL[H_];
  __shared__ unsigned int fcL[2];
  __shared__ float red[H_];
  __shared__ float part[352];
  int tid = threadIdx.x;
  int b = blockIdx.x;
  int lane = tid & 63;
  unsigned wvu = (unsigned)__builtin_amdgcn_readfirstlane(tid >> 6);
  float bias = h_bias[tid];
  unsigned myhi = rowhi[tid] << 12;
  float v, s, cnt;
  if (t0 == 0) { v = 0.f; s = 0.f; cnt = 0.f; }
  else { v = state_v[b * H_ + tid]; s = state_s[b * H_ + tid]; cnt = state_c[b * H_ + tid]; }
  accL[tid] = 0;
  if (tid < 2) fcL[tid] = 0;
  __syncthreads();
  {  // initial firing list from carried state
    bool f0 = s > 0.f;
    unsigned long long bb = __ballot(f0);
    unsigned n = (unsigned)__popcll(bb);
    unsigned pos = (unsigned)__popcll(bb & ((1ull << lane) - 1ull));
    unsigned wb = 0;
    if (lane == 0) wb = atomicAdd(&fcL[0], n);
    wb = (unsigned)__builtin_amdgcn_readfirstlane((int)wb);
    if (f0) listL[wb + pos] = (unsigned)tid | myhi;
  }
  __syncthreads();
  const float* dptr = drive + (size_t)b * Tc * H_ + tid;
  float dcur = dptr[0];
  for (int t = 0; t < Tc; ++t) {
    float dnxt = (t + 1 < Tc) ? dptr[(size_t)(t + 1) * H_] : 0.f;
    unsigned F = (unsigned)__builtin_amdgcn_readfirstlane((int)fcL[t & 1]);
    // wave wvu owns contiguous slots [F*wvu/16, F*(wvu+1)/16)
    unsigned lo = (F * wvu) >> 4;
    unsigned hi = (F * (wvu + 1u)) >> 4;
    for (unsigned i0 = lo; i0 < hi; i0 += 8u) {
      unsigned idx = i0 + ((unsigned)lane & 7u);
      unsigned packed = listL[idx < hi ? idx : (hi - 1u)];  // one ds_read per 8 slots
      // fan out to SGPRs; 1024 = dummy sentinel (scalar-guarded slots)
#define EDECL(n) unsigned e##n = (i0 + n##u < hi) ? (unsigned)__builtin_amdgcn_readlane((int)packed, n) : 1024u; \
                 unsigned ea##n = 0u, eb##n = 0u;
      EDECL(0) EDECL(1) EDECL(2) EDECL(3) EDECL(4) EDECL(5) EDECL(6) EDECL(7)
#undef EDECL
      // issue ALL loads before ANY atomic (named regs -> all stay in flight)
#define ELOAD(n) if (e##n != 1024u) { \
        const unsigned int* rp = csr + ((size_t)(e##n & 1023u) << 7); \
        ea##n = rp[lane]; \
        if (e##n & 4096u) eb##n = rp[64 + lane]; }
      ELOAD(0) ELOAD(1) ELOAD(2) ELOAD(3) ELOAD(4) ELOAD(5) ELOAD(6) ELOAD(7)
#undef ELOAD
#define EATOM(n) if (e##n != 1024u) { \
        atomicAdd(&accL[ea##n & 1023u], ((int)ea##n) >> 10); \
        if (e##n & 4096u) atomicAdd(&accL[eb##n & 1023u], ((int)eb##n) >> 10); }
      EATOM(0) EATOM(1) EATOM(2) EATOM(3) EATOM(4) EATOM(5) EATOM(6) EATOM(7)
#undef EATOM
    }
    __syncthreads();
    // -------- membrane update + next firing list --------
    int ri = accL[tid];
    accL[tid] = 0;
    float rec = (float)ri * 1.1920929e-7f;  // 2^-23
    v = BETA * v + (dcur + bias) + rec;
    bool f = v > THRESH;
    v -= f ? THRESH : 0.f;
    cnt += f ? 1.f : 0.f;
    s = f ? 1.f : 0.f;
    unsigned long long bb = __ballot(f);
    unsigned n = (unsigned)__popcll(bb);
    unsigned pos = (unsigned)__popcll(bb & ((1ull << lane) - 1ull));
    unsigned wb = 0;
    if (lane == 0) wb = atomicAdd(&fcL[(t + 1) & 1], n);
    wb = (unsigned)__builtin_amdgcn_readfirstlane((int)wb);
    if (f) listL[wb + pos] = (unsigned)tid | myhi;
    if (tid == 0) fcL[t & 1] = 0;
    dcur = dnxt;
    __syncthreads();
  }
  if (!last) {
    state_v[b * H_ + tid] = v; state_s[b * H_ + tid] = s; state_c[b * H_ + tid] = cnt;
  } else {
    red[tid] = cnt;
    __syncthreads();
    if (tid < 352) {
      int o = tid >> 5, seg = tid & 31;
      float p = 0.f;
      for (int j = 0; j < 32; ++j) {
        int hh = seg * 32 + j;
        p += red[hh] * W_out[hh * O_ + o];
      }
      part[tid] = p;
    }
    __syncthreads();
    if (tid < O_) {
      float sum = 0.f;
      for (int g = 0; g < 32; ++g) sum += part[(tid << 5) + g];
      out[b * O_ + tid] = b_out[tid] + sum * (1.0f / (float)T_);
    }
  }
}

extern "C" void kernel_launch(void* const* d_in, const int* in_sizes, int n_in,
                              void* d_out, int out_size, void* d_ws, size_t ws_size,
                              hipStream_t stream) {
  (void)in_sizes; (void)n_in; (void)out_size;
  const float* x = (const float*)d_in[0];
  const float* W_in = (const float*)d_in[1];
  const float* W_rec = (const float*)d_in[2];
  const float* W_out = (const float*)d_in[3];
  const float* h_bias = (const float*)d_in[4];
  const float* b_out = (const float*)d_in[5];
  const float* mask = (const float*)d_in[6];
  float* out = (float*)d_out;

  char* ws = (char*)d_ws;
  size_t off = 0;
  auto alloc = [&](size_t bytes) {
    void* p = ws + off;
    off = (off + bytes + 255) & ~(size_t)255;
    return p;
  };
  unsigned short* Wt = (unsigned short*)alloc((size_t)H_ * K2_ * 2);
  unsigned int* csr = (unsigned int*)alloc((size_t)(H_ + 1) * 128 * 4);  // +1 dummy row
  unsigned int* rowhi = (unsigned int*)alloc((size_t)(H_ + 1) * 4);
  float* st_v = (float*)alloc((size_t)B_ * H_ * 4);
  float* st_s = (float*)alloc((size_t)B_ * H_ * 4);
  float* st_c = (float*)alloc((size_t)B_ * H_ * 4);
  size_t fixed = off;

  size_t per_t = (size_t)128 * K2_ * 2 + (size_t)128 * 1024 * 4;
  int Tc = 1;
  if (ws_size > fixed + per_t) Tc = (int)((ws_size - fixed) / per_t);
  if (Tc > T_) Tc = T_;
  if (Tc < 1) Tc = 1;
  unsigned short* xs = (unsigned short*)alloc((size_t)128 * Tc * K2_ * 2);
  float* drive = (float*)alloc((size_t)128 * Tc * 1024 * 4);

  k_csr<<<dim3(257), dim3(256), 0, stream>>>(W_rec, mask, csr, rowhi);
  k_build_wt<<<dim3(6, 1024), dim3(256), 0, stream>>>(W_in, Wt);

  for (int t0 = 0; t0 < T_; t0 += Tc) {
    int tc = (Tc < T_ - t0) ? Tc : (T_ - t0);
    k_build_xs<<<dim3(32 * tc), dim3(256), 0, stream>>>(x, xs, t0, tc);
    k_gemm<<<dim3(tc, 4), dim3(512), 0, stream>>>(xs, Wt, drive);
    k_rsnn<<<dim3(128), dim3(1024), 0, stream>>>(drive, csr, rowhi, h_bias, W_out, b_out,
                                                 st_v, st_s, st_c, out, t0, tc,
                                                 (t0 + tc >= T_) ? 1 : 0);
  }
}